// Round 22
// baseline (3270.798 us; speedup 1.0000x reference)
//
#include <hip/hip_runtime.h>
#include <math.h>
#include <stdint.h>

// Problem dims (fixed by reference)
#define TT 128
#define BB 64
#define II 1024
#define HH 1024
#define KK 8
#define G4 4096   // 4*H
#define MM 8192   // T*B
#define TCH 32    // premix chunk: timesteps per chunk (256 MB buffer)
#define NCH (TT / TCH)

typedef _Float16 f16x8 __attribute__((ext_vector_type(8)));
typedef float    f32x4 __attribute__((ext_vector_type(4)));

// ---------------- workspace layout (bytes) ----------------
#define OFF_CW    0           // cw fp32 [T][K]
#define OFF_BIAS  4096        // bias fp32 [T][4H]
#define OFF_C     2101248     // c fp32 [B][H]
#define OFF_H0    2363392     // h f16 dbuf 0
#define OFF_H1    2494464     // h f16 dbuf 1
#define OFF_GX    2625536     // gates_x f16 [M][4H]
#define OFF_XF    203952128   // x f16 [M][II] = 16.8 MB (phaseA only)
#define OFF_WCH   69734400    // premix chunk f16 [TCH=32][256][32][64][8] = 256 MB
                              // (region reused after phaseA; phaseA reads w_ih
                              // fp32 directly now — no wihf buffer at all)
#define WS_REQ    338169856   // proven available (tier-2 ran in R5/R7)

// =========================================================
// softmax(coef) + mixed bias (all paths)
// =========================================================
__global__ __launch_bounds__(256) void softmax_bias_kernel(
    const float* __restrict__ coef,
    const float* __restrict__ b_ih,
    const float* __restrict__ b_hh,
    float* __restrict__ ws)
{
    int t = blockIdx.x;
    float c[KK];
    float m = -1e30f;
    #pragma unroll
    for (int k = 0; k < KK; ++k) { c[k] = coef[t*KK + k]; m = fmaxf(m, c[k]); }
    float s = 0.f;
    #pragma unroll
    for (int k = 0; k < KK; ++k) { c[k] = expf(c[k] - m); s += c[k]; }
    float inv = 1.f / s;
    #pragma unroll
    for (int k = 0; k < KK; ++k) c[k] *= inv;
    if (threadIdx.x < KK) ws[t*KK + threadIdx.x] = c[threadIdx.x];
    float* bias = ws + 1024;
    for (int g = threadIdx.x; g < G4; g += blockDim.x) {
        float acc = 0.f;
        #pragma unroll
        for (int k = 0; k < KK; ++k)
            acc += c[k] * (b_ih[k*G4 + g] + b_hh[k*G4 + g]);
        bias[t*G4 + g] = acc;
    }
}

// =========================================================
// setup kernels
// =========================================================
__global__ __launch_bounds__(256) void conv_f16_kernel(
    const float* __restrict__ src, _Float16* __restrict__ dst, long n8)
{
    long v = (long)blockIdx.x * 256 + threadIdx.x;
    if (v >= n8) return;
    const float* s = src + v * 8;
    f16x8 o;
    #pragma unroll
    for (int e = 0; e < 8; ++e) o[e] = (_Float16)s[e];
    *(f16x8*)(dst + v * 8) = o;
}

// Chunked premix: Wmix[t] = sum_k cw[t][k]*whh[k] for t in [t0, t0+TCH),
// written f16 in step packed order. High-occupancy (2048 blocks).
__global__ __launch_bounds__(256) void mix_chunk_kernel(
    const float* __restrict__ w_hh,   // [8][4096][1024] fp32
    const float* __restrict__ cw,     // [T][K]
    _Float16* __restrict__ wchunk,    // [TCH][256][32][64][8] f16
    int t0)
{
    __shared__ float cws[TCH * KK];   // 256 floats
    const int tid = threadIdx.x;
    if (tid < TCH * KK) cws[tid] = cw[t0 * KK + tid];

    long v = (long)blockIdx.x * 256 + tid;       // < 524288 slots
    const int l  = (int)(v & 63);
    const int kk = (int)((v >> 6) & 31);
    const int bj = (int)(v >> 11);
    const int q  = l & 15;
    const int grow = (q >> 2) * HH + bj * 4 + (q & 3);
    const int col  = kk * 32 + 8 * (l >> 4);

    float w8[KK][8];
    #pragma unroll
    for (int k = 0; k < KK; ++k) {
        const float* s = w_hh + ((size_t)k * G4 + grow) * II + col;
        #pragma unroll
        for (int e = 0; e < 8; ++e) w8[k][e] = s[e];
    }
    __syncthreads();

    const size_t slot = ((size_t)bj * 32 + kk) * 64 + l;   // *8 elems
    #pragma unroll 4
    for (int tt = 0; tt < TCH; ++tt) {
        float acc[8] = {0,0,0,0,0,0,0,0};
        #pragma unroll
        for (int k = 0; k < KK; ++k) {
            float c = cws[tt * KK + k];
            #pragma unroll
            for (int e = 0; e < 8; ++e) acc[e] += c * w8[k][e];
        }
        f16x8 o;
        #pragma unroll
        for (int e = 0; e < 8; ++e) o[e] = (_Float16)acc[e];
        *(f16x8*)(wchunk + ((size_t)tt << 22) + slot * 8) = o;
    }
}

__global__ __launch_bounds__(256) void hinit_kernel(
    const float* __restrict__ h0, _Float16* __restrict__ hws)
{
    int idx = blockIdx.x * 256 + threadIdx.x;
    hws[idx] = (_Float16)h0[idx];
}

// =========================================================
// Phase A v2b: as R18/R21 (A = unscaled xf f16, per-kseg fp32
// mixture fold) but B staged DIRECTLY from fp32 w_ih with
// in-register f16 conversion (same rounding as conv_f16 ->
// bit-identical values). Deletes the wih conversion kernel.
// =========================================================
#define PAD 80
__global__ __launch_bounds__(256) void phaseA2b_gemm(
    const _Float16* __restrict__ xf,   // [M][II] f16, unscaled
    const float* __restrict__ wih,     // [K][4H][II] fp32 (input tensor)
    const float* __restrict__ cw,      // [T][K] fp32
    _Float16* __restrict__ gx)         // [M][4H] f16
{
    __shared__ _Float16 As[128][PAD];
    __shared__ _Float16 Bs[128][PAD];
    const int tid  = threadIdx.x;
    const int lane = tid & 63;
    const int wv   = tid >> 6;
    const int wr   = wv >> 1, wc = wv & 1;
    const int bm   = blockIdx.x & 63;
    const int bn   = blockIdx.x >> 6;
    const size_t m0 = (size_t)bm * 128, n0 = (size_t)bn * 128;

    // wave-uniform timestep: rows wr*64 .. wr*64+63 => t = bm*2 + wr
    const int t_wave = bm * 2 + wr;
    float sc[KK];
    #pragma unroll
    for (int k = 0; k < KK; ++k) sc[k] = cw[t_wave * KK + k];

    f32x4 accT[4][4], accP[4][4];
    #pragma unroll
    for (int i = 0; i < 4; ++i)
        #pragma unroll
        for (int j = 0; j < 4; ++j) {
            accT[i][j] = (f32x4){0.f,0.f,0.f,0.f};
            accP[i][j] = (f32x4){0.f,0.f,0.f,0.f};
        }

    const int srow = tid >> 3;
    const int scol = (tid & 7) * 8;

    for (int kt = 0; kt < 128; ++kt) {
        const int kseg = kt >> 4;
        const int i0   = (kt & 15) * 64;
        const size_t bbase = (size_t)kseg * G4 * II + i0;
        #pragma unroll
        for (int it = 0; it < 4; ++it) {
            int r = it * 32 + srow;
            *(f16x8*)&As[r][scol] = *(const f16x8*)(xf + (m0 + r) * II + i0 + scol);
            // B: fp32 load + convert (identical rounding to conv_f16)
            const float* bs = wih + bbase + (n0 + r) * II + scol;
            f16x8 o;
            #pragma unroll
            for (int e = 0; e < 8; ++e) o[e] = (_Float16)bs[e];
            *(f16x8*)&Bs[r][scol] = o;
        }
        __syncthreads();
        #pragma unroll
        for (int half = 0; half < 2; ++half) {
            const int kc = half * 32 + 8 * (lane >> 4);
            f16x8 a[4], b[4];
            #pragma unroll
            for (int mf = 0; mf < 4; ++mf)
                a[mf] = *(const f16x8*)&As[wr*64 + mf*16 + (lane & 15)][kc];
            #pragma unroll
            for (int nf = 0; nf < 4; ++nf)
                b[nf] = *(const f16x8*)&Bs[wc*64 + nf*16 + (lane & 15)][kc];
            #pragma unroll
            for (int mf = 0; mf < 4; ++mf)
                #pragma unroll
                for (int nf = 0; nf < 4; ++nf)
                    accP[mf][nf] = __builtin_amdgcn_mfma_f32_16x16x32_f16(
                        a[mf], b[nf], accP[mf][nf], 0, 0, 0);
        }
        __syncthreads();
        // kseg boundary: fold scaled partial into total
        if ((kt & 15) == 15) {
            const float s = sc[kseg];
            #pragma unroll
            for (int mf = 0; mf < 4; ++mf)
                #pragma unroll
                for (int nf = 0; nf < 4; ++nf) {
                    #pragma unroll
                    for (int r = 0; r < 4; ++r)
                        accT[mf][nf][r] += s * accP[mf][nf][r];
                    accP[mf][nf] = (f32x4){0.f,0.f,0.f,0.f};
                }
        }
    }
    #pragma unroll
    for (int mf = 0; mf < 4; ++mf)
        #pragma unroll
        for (int nf = 0; nf < 4; ++nf) {
            size_t col = n0 + wc*64 + nf*16 + (lane & 15);
            size_t rw  = m0 + wr*64 + mf*16 + 4*(lane >> 4);
            #pragma unroll
            for (int r = 0; r < 4; ++r)
                gx[(rw + r) * G4 + col] = (_Float16)accT[mf][nf][r];
        }
}

// =========================================================
// Phase B v7 (R21-verified, best): batch-halved blocks ->
// 512 blocks x 512 thr = 2 blocks/CU.
// =========================================================
__global__ __launch_bounds__(512) void stepB7_kernel(
    const _Float16* __restrict__ wmix_t, // [256][32][64][8] for this t
    const _Float16* __restrict__ gx_t,   // [64][4096]
    const float* __restrict__ bias_t,    // [4096]
    const _Float16* __restrict__ hin,    // [64][1024]
    _Float16* __restrict__ hout,         // [64][1024]
    float* __restrict__ cst,             // [64][1024]
    float* __restrict__ out_t)           // [64][1024]
{
    __shared__ float gpart[8][32][17];   // 17.4 KB

    const int tid  = threadIdx.x;
    const int lane = tid & 63;
    const int wv   = tid >> 6;           // 0..7
    const int bj   = blockIdx.x >> 1;    // j-group 0..255
    const int bh   = blockIdx.x & 1;     // batch half
    const int j0   = bj * 4;
    const int b0   = bh * 32;
    const int q    = lane & 15;
    const int kch  = 8 * (lane >> 4);    // k-chunk within 32

    // ---- early epilogue prefetch (tid < 128: eb 0..31, ejj 0..3) ----
    float pre_gx[4], pre_bias[4], pre_c = 0.f;
    const int eb  = tid & 31;
    const int ejj = (tid >> 5) & 3;
    if (tid < 128) {
        #pragma unroll
        for (int gate = 0; gate < 4; ++gate) {
            pre_gx[gate]   = (float)gx_t[(size_t)(b0 + eb) * G4 + gate * HH + j0 + ejj];
            pre_bias[gate] = bias_t[gate * HH + j0 + ejj];
        }
        pre_c = cst[(size_t)(b0 + eb) * HH + j0 + ejj];
    }

    // wave's contiguous 4 KB weight run: kk in [4wv, 4wv+4)
    const _Float16* w0 = wmix_t + (((size_t)bj * 32 + 4 * wv) * 64) * 8;
    f16x8 pb[4];
    #pragma unroll
    for (int u = 0; u < 4; ++u)
        pb[u] = *(const f16x8*)(w0 + ((size_t)u * 64 + lane) * 8);

    f32x4 acc[2];
    #pragma unroll
    for (int mf = 0; mf < 2; ++mf) acc[mf] = (f32x4){0.f,0.f,0.f,0.f};

    #pragma unroll
    for (int u = 0; u < 4; ++u) {
        const int kk = 4 * wv + u;
        const int hp = kk * 32 + kch;
        f16x8 a[2];
        #pragma unroll
        for (int mf = 0; mf < 2; ++mf)
            a[mf] = *(const f16x8*)(hin + (size_t)(b0 + mf * 16 + q) * HH + hp);
        #pragma unroll
        for (int mf = 0; mf < 2; ++mf)
            acc[mf] = __builtin_amdgcn_mfma_f32_16x16x32_f16(a[mf], pb[u], acc[mf], 0, 0, 0);
    }

    #pragma unroll
    for (int mf = 0; mf < 2; ++mf) {
        #pragma unroll
        for (int r = 0; r < 4; ++r) {
            int m = mf * 16 + 4 * (lane >> 4) + r;   // local b 0..31
            gpart[wv][m][q] = acc[mf][r];
        }
    }
    __syncthreads();

    // epilogue: first 128 threads, thread = (eb, ejj)
    if (tid < 128) {
        const int j = j0 + ejj;
        const int gb = b0 + eb;
        float gval[4];
        #pragma unroll
        for (int gate = 0; gate < 4; ++gate) {
            int qq = gate * 4 + ejj;
            float v = 0.f;
            #pragma unroll
            for (int w = 0; w < 8; ++w) v += gpart[w][eb][qq];
            gval[gate] = v + pre_gx[gate] + pre_bias[gate];
        }
        float iv = 1.f / (1.f + expf(-gval[0]));
        float fv = 1.f / (1.f + expf(-gval[1]));
        float gv = tanhf(gval[2]);
        float ov = 1.f / (1.f + expf(-gval[3]));
        float c  = fv * pre_c + iv * gv;
        cst[(size_t)gb * HH + j] = c;
        float h  = ov * tanhf(c);
        out_t[(size_t)gb * HH + j] = h;
        hout[(size_t)gb * HH + j] = (_Float16)h;
    }
}

// =========================================================
// FALLBACK (R3, verified): fused per-step mixture kernel
// =========================================================
#define TI 128
__global__ __launch_bounds__(256) void step_kernel(
    const float* __restrict__ x_t, const float* __restrict__ hprev,
    const float* __restrict__ cprev, const float* __restrict__ w_ih,
    const float* __restrict__ w_hh, const float* __restrict__ cw_t,
    const float* __restrict__ bias_t, float* __restrict__ cstate,
    float* __restrict__ out_t)
{
    __shared__ float xh_s[BB][TI + 1];
    __shared__ float w_s[16][TI + 1];
    __shared__ float gex[4 * BB * 4];
    const int tid = threadIdx.x;
    const int j0 = blockIdx.x * 4;
    const int b = tid & 63;
    const int gate = tid >> 6;
    float cw[KK];
    #pragma unroll
    for (int k = 0; k < KK; ++k) cw[k] = cw_t[k];
    float acc[4] = {0.f, 0.f, 0.f, 0.f};
    for (int ci = 0; ci < II + HH; ci += TI) {
        for (int e = tid; e < BB * TI; e += 256) {
            int bb = e >> 7, cc = e & (TI - 1);
            int c = ci + cc;
            xh_s[bb][cc] = (c < II) ? x_t[bb * II + c] : hprev[bb * HH + (c - II)];
        }
        const float* wbase = (ci < II) ? w_ih : w_hh;
        const int cbase = (ci < II) ? ci : (ci - II);
        for (int e = tid; e < 16 * TI; e += 256) {
            int r = e >> 7, cc = e & (TI - 1);
            int grw = (r >> 2) * HH + j0 + (r & 3);
            size_t off = (size_t)grw * II + (size_t)(cbase + cc);
            float wm = 0.f;
            #pragma unroll
            for (int k = 0; k < KK; ++k)
                wm += cw[k] * wbase[(size_t)k * ((size_t)G4 * II) + off];
            w_s[r][cc] = wm;
        }
        __syncthreads();
        for (int c = 0; c < TI; ++c) {
            float xv = xh_s[b][c];
            #pragma unroll
            for (int d = 0; d < 4; ++d)
                acc[d] += xv * w_s[(gate << 2) + d][c];
        }
        __syncthreads();
    }
    #pragma unroll
    for (int d = 0; d < 4; ++d) {
        acc[d] += bias_t[gate * HH + j0 + d];
        gex[gate * 256 + b * 4 + d] = acc[d];
    }
    __syncthreads();
    const int b2 = tid & 63, d2 = tid >> 6;
    float iv = gex[0 * 256 + b2 * 4 + d2];
    float fv = gex[1 * 256 + b2 * 4 + d2];
    float gv = gex[2 * 256 + b2 * 4 + d2];
    float ov = gex[3 * 256 + b2 * 4 + d2];
    float si = 1.f / (1.f + expf(-iv));
    float sf = 1.f / (1.f + expf(-fv));
    float so = 1.f / (1.f + expf(-ov));
    float tg = tanhf(gv);
    int j = j0 + d2;
    float cold = cprev[b2 * HH + j];
    float cnew = sf * cold + si * tg;
    cstate[b2 * HH + j] = cnew;
    out_t[b2 * HH + j] = so * tanhf(cnew);
}

// =========================================================
extern "C" void kernel_launch(void* const* d_in, const int* in_sizes, int n_in,
                              void* d_out, int out_size, void* d_ws, size_t ws_size,
                              hipStream_t stream) {
    const float* x    = (const float*)d_in[0];
    const float* coef = (const float*)d_in[1];
    const float* w_ih = (const float*)d_in[2];
    const float* w_hh = (const float*)d_in[3];
    const float* b_ih = (const float*)d_in[4];
    const float* b_hh = (const float*)d_in[5];
    const float* h0   = (const float*)d_in[6];
    const float* c0   = (const float*)d_in[7];
    float* out = (float*)d_out;
    char* ws   = (char*)d_ws;
    float* cw_f   = (float*)(ws + OFF_CW);
    float* bias_f = (float*)(ws + OFF_BIAS);
    float* c_f    = (float*)(ws + OFF_C);

    softmax_bias_kernel<<<TT, 256, 0, stream>>>(coef, b_ih, b_hh, (float*)ws);

    if (ws_size >= (size_t)WS_REQ) {
        _Float16* h0p = (_Float16*)(ws + OFF_H0);
        _Float16* h1p = (_Float16*)(ws + OFF_H1);
        _Float16* gx  = (_Float16*)(ws + OFF_GX);
        _Float16* xf  = (_Float16*)(ws + OFF_XF);
        _Float16* wch = (_Float16*)(ws + OFF_WCH);

        conv_f16_kernel<<<4096, 256, 0, stream>>>(x, xf, (long)MM*II/8);
        hinit_kernel<<<256, 256, 0, stream>>>(h0, h0p);
        hipMemcpyAsync(c_f, c0, (size_t)BB*HH*4, hipMemcpyDeviceToDevice, stream);

        phaseA2b_gemm<<<2048, 256, 0, stream>>>(xf, w_ih, cw_f, gx);

        // chunked premix + steps (stream-serial => region reuse is safe)
        for (int ch = 0; ch < NCH; ++ch) {
            const int t0 = ch * TCH;
            mix_chunk_kernel<<<2048, 256, 0, stream>>>(w_hh, cw_f, wch, t0);
            for (int tt = 0; tt < TCH; ++tt) {
                const int t = t0 + tt;
                stepB7_kernel<<<512, 512, 0, stream>>>(
                    wch + ((size_t)tt << 22),
                    gx + (size_t)t * BB * G4,
                    bias_f + (size_t)t * G4,
                    (t & 1) ? h1p : h0p,
                    (t & 1) ? h0p : h1p,
                    c_f,
                    out + (size_t)t * BB * HH);
            }
        }
    } else {
        for (int t = 0; t < TT; ++t) {
            const float* xt    = x + (size_t)t * BB * II;
            const float* hprev = (t == 0) ? h0 : out + (size_t)(t - 1) * BB * HH;
            const float* cprev = (t == 0) ? c0 : c_f;
            step_kernel<<<HH / 4, 256, 0, stream>>>(
                xt, hprev, cprev, w_ih, w_hh,
                cw_f + (size_t)t * KK,
                bias_f + (size_t)t * G4,
                c_f,
                out + (size_t)t * BB * HH);
        }
    }
}

// Round 23
// 2227.216 us; speedup vs baseline: 1.4686x; 1.4686x over previous
//
#include <hip/hip_runtime.h>
#include <math.h>
#include <stdint.h>

// Problem dims (fixed by reference)
#define TT 128
#define BB 64
#define II 1024
#define HH 1024
#define KK 8
#define G4 4096   // 4*H
#define MM 8192   // T*B
#define TCH 32    // premix chunk: timesteps per chunk (256 MB buffer)
#define NCH (TT / TCH)

typedef _Float16 f16x8 __attribute__((ext_vector_type(8)));
typedef float    f32x4 __attribute__((ext_vector_type(4)));

// ---------------- workspace layout (bytes) ----------------
#define OFF_CW    0           // cw fp32 [T][K]
#define OFF_BIAS  4096        // bias fp32 [T][4H]
#define OFF_C     2101248     // c fp32 [B][H]
#define OFF_H0    2363392     // h f16 dbuf 0
#define OFF_H1    2494464     // h f16 dbuf 1
#define OFF_GX    2625536     // gates_x f16 [M][4H]
#define OFF_WIH   69734400    // wih f16 [K][4H][I]   (phaseA only)
#define OFF_XF    203952128   // x f16 [M][II] = 16.8 MB (phaseA only)
#define OFF_WCH   OFF_WIH     // premix chunk f16 [TCH=32][256][32][64][8] = 256 MB
                              // aliases wih+xf region (both dead after phaseA)
#define WS_REQ    338169856   // proven available (tier-2 ran in R5/R7)

// =========================================================
// softmax(coef) + mixed bias (all paths)
// =========================================================
__global__ __launch_bounds__(256) void softmax_bias_kernel(
    const float* __restrict__ coef,
    const float* __restrict__ b_ih,
    const float* __restrict__ b_hh,
    float* __restrict__ ws)
{
    int t = blockIdx.x;
    float c[KK];
    float m = -1e30f;
    #pragma unroll
    for (int k = 0; k < KK; ++k) { c[k] = coef[t*KK + k]; m = fmaxf(m, c[k]); }
    float s = 0.f;
    #pragma unroll
    for (int k = 0; k < KK; ++k) { c[k] = expf(c[k] - m); s += c[k]; }
    float inv = 1.f / s;
    #pragma unroll
    for (int k = 0; k < KK; ++k) c[k] *= inv;
    if (threadIdx.x < KK) ws[t*KK + threadIdx.x] = c[threadIdx.x];
    float* bias = ws + 1024;
    for (int g = threadIdx.x; g < G4; g += blockDim.x) {
        float acc = 0.f;
        #pragma unroll
        for (int k = 0; k < KK; ++k)
            acc += c[k] * (b_ih[k*G4 + g] + b_hh[k*G4 + g]);
        bias[t*G4 + g] = acc;
    }
}

// =========================================================
// setup kernels
// =========================================================
__global__ __launch_bounds__(256) void conv_f16_kernel(
    const float* __restrict__ src, _Float16* __restrict__ dst, long n8)
{
    long v = (long)blockIdx.x * 256 + threadIdx.x;
    if (v >= n8) return;
    const float* s = src + v * 8;
    f16x8 o;
    #pragma unroll
    for (int e = 0; e < 8; ++e) o[e] = (_Float16)s[e];
    *(f16x8*)(dst + v * 8) = o;
}

// Chunked premix: Wmix[t] = sum_k cw[t][k]*whh[k] for t in [t0, t0+TCH),
// written f16 in step packed order. High-occupancy (2048 blocks).
__global__ __launch_bounds__(256) void mix_chunk_kernel(
    const float* __restrict__ w_hh,   // [8][4096][1024] fp32
    const float* __restrict__ cw,     // [T][K]
    _Float16* __restrict__ wchunk,    // [TCH][256][32][64][8] f16
    int t0)
{
    __shared__ float cws[TCH * KK];   // 256 floats
    const int tid = threadIdx.x;
    if (tid < TCH * KK) cws[tid] = cw[t0 * KK + tid];

    long v = (long)blockIdx.x * 256 + tid;       // < 524288 slots
    const int l  = (int)(v & 63);
    const int kk = (int)((v >> 6) & 31);
    const int bj = (int)(v >> 11);
    const int q  = l & 15;
    const int grow = (q >> 2) * HH + bj * 4 + (q & 3);
    const int col  = kk * 32 + 8 * (l >> 4);

    float w8[KK][8];
    #pragma unroll
    for (int k = 0; k < KK; ++k) {
        const float* s = w_hh + ((size_t)k * G4 + grow) * II + col;
        #pragma unroll
        for (int e = 0; e < 8; ++e) w8[k][e] = s[e];
    }
    __syncthreads();

    const size_t slot = ((size_t)bj * 32 + kk) * 64 + l;   // *8 elems
    #pragma unroll 4
    for (int tt = 0; tt < TCH; ++tt) {
        float acc[8] = {0,0,0,0,0,0,0,0};
        #pragma unroll
        for (int k = 0; k < KK; ++k) {
            float c = cws[tt * KK + k];
            #pragma unroll
            for (int e = 0; e < 8; ++e) acc[e] += c * w8[k][e];
        }
        f16x8 o;
        #pragma unroll
        for (int e = 0; e < 8; ++e) o[e] = (_Float16)acc[e];
        *(f16x8*)(wchunk + ((size_t)tt << 22) + slot * 8) = o;
    }
}

__global__ __launch_bounds__(256) void hinit_kernel(
    const float* __restrict__ h0, _Float16* __restrict__ hws)
{
    int idx = blockIdx.x * 256 + threadIdx.x;
    hws[idx] = (_Float16)h0[idx];
}

// =========================================================
// Phase A v2 (R18/R21-verified, 652 us): A = unscaled xf, mixture
// scale folded per kseg in fp32 (wave-uniform t). 116 VGPR —
// occupancy-fragile: do NOT add register pressure (R22 lesson).
// =========================================================
#define PAD 80
__global__ __launch_bounds__(256) void phaseA2_gemm(
    const _Float16* __restrict__ xf,   // [M][II] f16, unscaled
    const _Float16* __restrict__ wih,  // [K][4H][II] f16
    const float* __restrict__ cw,      // [T][K] fp32
    _Float16* __restrict__ gx)         // [M][4H] f16
{
    __shared__ _Float16 As[128][PAD];
    __shared__ _Float16 Bs[128][PAD];
    const int tid  = threadIdx.x;
    const int lane = tid & 63;
    const int wv   = tid >> 6;
    const int wr   = wv >> 1, wc = wv & 1;
    const int bm   = blockIdx.x & 63;
    const int bn   = blockIdx.x >> 6;
    const size_t m0 = (size_t)bm * 128, n0 = (size_t)bn * 128;

    // wave-uniform timestep: rows wr*64 .. wr*64+63 => t = bm*2 + wr
    const int t_wave = bm * 2 + wr;
    float sc[KK];
    #pragma unroll
    for (int k = 0; k < KK; ++k) sc[k] = cw[t_wave * KK + k];

    f32x4 accT[4][4], accP[4][4];
    #pragma unroll
    for (int i = 0; i < 4; ++i)
        #pragma unroll
        for (int j = 0; j < 4; ++j) {
            accT[i][j] = (f32x4){0.f,0.f,0.f,0.f};
            accP[i][j] = (f32x4){0.f,0.f,0.f,0.f};
        }

    const int srow = tid >> 3;
    const int scol = (tid & 7) * 8;

    for (int kt = 0; kt < 128; ++kt) {
        const int kseg = kt >> 4;
        const int i0   = (kt & 15) * 64;
        const size_t bbase = (size_t)kseg * G4 * II + i0;
        #pragma unroll
        for (int it = 0; it < 4; ++it) {
            int r = it * 32 + srow;
            *(f16x8*)&As[r][scol] = *(const f16x8*)(xf + (m0 + r) * II + i0 + scol);
            *(f16x8*)&Bs[r][scol] = *(const f16x8*)(wih + bbase + (n0 + r) * II + scol);
        }
        __syncthreads();
        #pragma unroll
        for (int half = 0; half < 2; ++half) {
            const int kc = half * 32 + 8 * (lane >> 4);
            f16x8 a[4], b[4];
            #pragma unroll
            for (int mf = 0; mf < 4; ++mf)
                a[mf] = *(const f16x8*)&As[wr*64 + mf*16 + (lane & 15)][kc];
            #pragma unroll
            for (int nf = 0; nf < 4; ++nf)
                b[nf] = *(const f16x8*)&Bs[wc*64 + nf*16 + (lane & 15)][kc];
            #pragma unroll
            for (int mf = 0; mf < 4; ++mf)
                #pragma unroll
                for (int nf = 0; nf < 4; ++nf)
                    accP[mf][nf] = __builtin_amdgcn_mfma_f32_16x16x32_f16(
                        a[mf], b[nf], accP[mf][nf], 0, 0, 0);
        }
        __syncthreads();
        // kseg boundary: fold scaled partial into total
        if ((kt & 15) == 15) {
            const float s = sc[kseg];
            #pragma unroll
            for (int mf = 0; mf < 4; ++mf)
                #pragma unroll
                for (int nf = 0; nf < 4; ++nf) {
                    #pragma unroll
                    for (int r = 0; r < 4; ++r)
                        accT[mf][nf][r] += s * accP[mf][nf][r];
                    accP[mf][nf] = (f32x4){0.f,0.f,0.f,0.f};
                }
        }
    }
    #pragma unroll
    for (int mf = 0; mf < 4; ++mf)
        #pragma unroll
        for (int nf = 0; nf < 4; ++nf) {
            size_t col = n0 + wc*64 + nf*16 + (lane & 15);
            size_t rw  = m0 + wr*64 + mf*16 + 4*(lane >> 4);
            #pragma unroll
            for (int r = 0; r < 4; ++r)
                gx[(rw + r) * G4 + col] = (_Float16)accT[mf][nf][r];
        }
}

// =========================================================
// Phase B v7 (R21-verified, best): batch-halved blocks ->
// 512 blocks x 512 thr = 2 blocks/CU.
// =========================================================
__global__ __launch_bounds__(512) void stepB7_kernel(
    const _Float16* __restrict__ wmix_t, // [256][32][64][8] for this t
    const _Float16* __restrict__ gx_t,   // [64][4096]
    const float* __restrict__ bias_t,    // [4096]
    const _Float16* __restrict__ hin,    // [64][1024]
    _Float16* __restrict__ hout,         // [64][1024]
    float* __restrict__ cst,             // [64][1024]
    float* __restrict__ out_t)           // [64][1024]
{
    __shared__ float gpart[8][32][17];   // 17.4 KB

    const int tid  = threadIdx.x;
    const int lane = tid & 63;
    const int wv   = tid >> 6;           // 0..7
    const int bj   = blockIdx.x >> 1;    // j-group 0..255
    const int bh   = blockIdx.x & 1;     // batch half
    const int j0   = bj * 4;
    const int b0   = bh * 32;
    const int q    = lane & 15;
    const int kch  = 8 * (lane >> 4);    // k-chunk within 32

    // ---- early epilogue prefetch (tid < 128: eb 0..31, ejj 0..3) ----
    float pre_gx[4], pre_bias[4], pre_c = 0.f;
    const int eb  = tid & 31;
    const int ejj = (tid >> 5) & 3;
    if (tid < 128) {
        #pragma unroll
        for (int gate = 0; gate < 4; ++gate) {
            pre_gx[gate]   = (float)gx_t[(size_t)(b0 + eb) * G4 + gate * HH + j0 + ejj];
            pre_bias[gate] = bias_t[gate * HH + j0 + ejj];
        }
        pre_c = cst[(size_t)(b0 + eb) * HH + j0 + ejj];
    }

    // wave's contiguous 4 KB weight run: kk in [4wv, 4wv+4)
    const _Float16* w0 = wmix_t + (((size_t)bj * 32 + 4 * wv) * 64) * 8;
    f16x8 pb[4];
    #pragma unroll
    for (int u = 0; u < 4; ++u)
        pb[u] = *(const f16x8*)(w0 + ((size_t)u * 64 + lane) * 8);

    f32x4 acc[2];
    #pragma unroll
    for (int mf = 0; mf < 2; ++mf) acc[mf] = (f32x4){0.f,0.f,0.f,0.f};

    #pragma unroll
    for (int u = 0; u < 4; ++u) {
        const int kk = 4 * wv + u;
        const int hp = kk * 32 + kch;
        f16x8 a[2];
        #pragma unroll
        for (int mf = 0; mf < 2; ++mf)
            a[mf] = *(const f16x8*)(hin + (size_t)(b0 + mf * 16 + q) * HH + hp);
        #pragma unroll
        for (int mf = 0; mf < 2; ++mf)
            acc[mf] = __builtin_amdgcn_mfma_f32_16x16x32_f16(a[mf], pb[u], acc[mf], 0, 0, 0);
    }

    #pragma unroll
    for (int mf = 0; mf < 2; ++mf) {
        #pragma unroll
        for (int r = 0; r < 4; ++r) {
            int m = mf * 16 + 4 * (lane >> 4) + r;   // local b 0..31
            gpart[wv][m][q] = acc[mf][r];
        }
    }
    __syncthreads();

    // epilogue: first 128 threads, thread = (eb, ejj)
    if (tid < 128) {
        const int j = j0 + ejj;
        const int gb = b0 + eb;
        float gval[4];
        #pragma unroll
        for (int gate = 0; gate < 4; ++gate) {
            int qq = gate * 4 + ejj;
            float v = 0.f;
            #pragma unroll
            for (int w = 0; w < 8; ++w) v += gpart[w][eb][qq];
            gval[gate] = v + pre_gx[gate] + pre_bias[gate];
        }
        float iv = 1.f / (1.f + expf(-gval[0]));
        float fv = 1.f / (1.f + expf(-gval[1]));
        float gv = tanhf(gval[2]);
        float ov = 1.f / (1.f + expf(-gval[3]));
        float c  = fv * pre_c + iv * gv;
        cst[(size_t)gb * HH + j] = c;
        float h  = ov * tanhf(c);
        out_t[(size_t)gb * HH + j] = h;
        hout[(size_t)gb * HH + j] = (_Float16)h;
    }
}

// =========================================================
// FALLBACK (R3, verified): fused per-step mixture kernel
// =========================================================
#define TI 128
__global__ __launch_bounds__(256) void step_kernel(
    const float* __restrict__ x_t, const float* __restrict__ hprev,
    const float* __restrict__ cprev, const float* __restrict__ w_ih,
    const float* __restrict__ w_hh, const float* __restrict__ cw_t,
    const float* __restrict__ bias_t, float* __restrict__ cstate,
    float* __restrict__ out_t)
{
    __shared__ float xh_s[BB][TI + 1];
    __shared__ float w_s[16][TI + 1];
    __shared__ float gex[4 * BB * 4];
    const int tid = threadIdx.x;
    const int j0 = blockIdx.x * 4;
    const int b = tid & 63;
    const int gate = tid >> 6;
    float cw[KK];
    #pragma unroll
    for (int k = 0; k < KK; ++k) cw[k] = cw_t[k];
    float acc[4] = {0.f, 0.f, 0.f, 0.f};
    for (int ci = 0; ci < II + HH; ci += TI) {
        for (int e = tid; e < BB * TI; e += 256) {
            int bb = e >> 7, cc = e & (TI - 1);
            int c = ci + cc;
            xh_s[bb][cc] = (c < II) ? x_t[bb * II + c] : hprev[bb * HH + (c - II)];
        }
        const float* wbase = (ci < II) ? w_ih : w_hh;
        const int cbase = (ci < II) ? ci : (ci - II);
        for (int e = tid; e < 16 * TI; e += 256) {
            int r = e >> 7, cc = e & (TI - 1);
            int grw = (r >> 2) * HH + j0 + (r & 3);
            size_t off = (size_t)grw * II + (size_t)(cbase + cc);
            float wm = 0.f;
            #pragma unroll
            for (int k = 0; k < KK; ++k)
                wm += cw[k] * wbase[(size_t)k * ((size_t)G4 * II) + off];
            w_s[r][cc] = wm;
        }
        __syncthreads();
        for (int c = 0; c < TI; ++c) {
            float xv = xh_s[b][c];
            #pragma unroll
            for (int d = 0; d < 4; ++d)
                acc[d] += xv * w_s[(gate << 2) + d][c];
        }
        __syncthreads();
    }
    #pragma unroll
    for (int d = 0; d < 4; ++d) {
        acc[d] += bias_t[gate * HH + j0 + d];
        gex[gate * 256 + b * 4 + d] = acc[d];
    }
    __syncthreads();
    const int b2 = tid & 63, d2 = tid >> 6;
    float iv = gex[0 * 256 + b2 * 4 + d2];
    float fv = gex[1 * 256 + b2 * 4 + d2];
    float gv = gex[2 * 256 + b2 * 4 + d2];
    float ov = gex[3 * 256 + b2 * 4 + d2];
    float si = 1.f / (1.f + expf(-iv));
    float sf = 1.f / (1.f + expf(-fv));
    float so = 1.f / (1.f + expf(-ov));
    float tg = tanhf(gv);
    int j = j0 + d2;
    float cold = cprev[b2 * HH + j];
    float cnew = sf * cold + si * tg;
    cstate[b2 * HH + j] = cnew;
    out_t[b2 * HH + j] = so * tanhf(cnew);
}

// =========================================================
extern "C" void kernel_launch(void* const* d_in, const int* in_sizes, int n_in,
                              void* d_out, int out_size, void* d_ws, size_t ws_size,
                              hipStream_t stream) {
    const float* x    = (const float*)d_in[0];
    const float* coef = (const float*)d_in[1];
    const float* w_ih = (const float*)d_in[2];
    const float* w_hh = (const float*)d_in[3];
    const float* b_ih = (const float*)d_in[4];
    const float* b_hh = (const float*)d_in[5];
    const float* h0   = (const float*)d_in[6];
    const float* c0   = (const float*)d_in[7];
    float* out = (float*)d_out;
    char* ws   = (char*)d_ws;
    float* cw_f   = (float*)(ws + OFF_CW);
    float* bias_f = (float*)(ws + OFF_BIAS);
    float* c_f    = (float*)(ws + OFF_C);

    softmax_bias_kernel<<<TT, 256, 0, stream>>>(coef, b_ih, b_hh, (float*)ws);

    if (ws_size >= (size_t)WS_REQ) {
        _Float16* h0p  = (_Float16*)(ws + OFF_H0);
        _Float16* h1p  = (_Float16*)(ws + OFF_H1);
        _Float16* gx   = (_Float16*)(ws + OFF_GX);
        _Float16* wihf = (_Float16*)(ws + OFF_WIH);
        _Float16* xf   = (_Float16*)(ws + OFF_XF);
        _Float16* wch  = (_Float16*)(ws + OFF_WCH);   // aliases wih+xf (dead after phaseA)

        conv_f16_kernel<<<16384, 256, 0, stream>>>(w_ih, wihf, (long)KK*G4*II/8);
        conv_f16_kernel<<<4096, 256, 0, stream>>>(x, xf, (long)MM*II/8);
        hinit_kernel<<<256, 256, 0, stream>>>(h0, h0p);
        hipMemcpyAsync(c_f, c0, (size_t)BB*HH*4, hipMemcpyDeviceToDevice, stream);

        phaseA2_gemm<<<2048, 256, 0, stream>>>(xf, wihf, cw_f, gx);

        // chunked premix + steps (stream-serial => region reuse is safe)
        for (int ch = 0; ch < NCH; ++ch) {
            const int t0 = ch * TCH;
            mix_chunk_kernel<<<2048, 256, 0, stream>>>(w_hh, cw_f, wch, t0);
            for (int tt = 0; tt < TCH; ++tt) {
                const int t = t0 + tt;
                stepB7_kernel<<<512, 512, 0, stream>>>(
                    wch + ((size_t)tt << 22),
                    gx + (size_t)t * BB * G4,
                    bias_f + (size_t)t * G4,
                    (t & 1) ? h1p : h0p,
                    (t & 1) ? h0p : h1p,
                    c_f,
                    out + (size_t)t * BB * HH);
            }
        }
    } else {
        for (int t = 0; t < TT; ++t) {
            const float* xt    = x + (size_t)t * BB * II;
            const float* hprev = (t == 0) ? h0 : out + (size_t)(t - 1) * BB * HH;
            const float* cprev = (t == 0) ? c0 : c_f;
            step_kernel<<<HH / 4, 256, 0, stream>>>(
                xt, hprev, cprev, w_ih, w_hh,
                cw_f + (size_t)t * KK,
                bias_f + (size_t)t * G4,
                c_f,
                out + (size_t)t * BB * HH);
        }
    }
}